// Round 6
// baseline (1559.189 us; speedup 1.0000x reference)
//
#include <hip/hip_runtime.h>

typedef _Float16 HALF;
typedef _Float16 f16x8 __attribute__((ext_vector_type(8)));
typedef float f32x4 __attribute__((ext_vector_type(4)));
typedef float f32x16 __attribute__((ext_vector_type(16)));
typedef int i32x4 __attribute__((ext_vector_type(4)));

// ---- fused weight conversion: fp32 (27*CI, CO) -> fp16 tiled [KP/TG][CO_PAD][TG]
// TG=16 for 32x32x16-MFMA layers, TG=32 for 16x16x32-MFMA layers.
struct WArgs { const float* W[8]; HALF* dst[8]; };

__global__ void convert_all_w_kernel(WArgs a)
{
    const int CIs[8]  = {64, 64, 64, 64, 32, 32, 16, 16};
    const int COs[8]  = {64, 64, 64, 32, 32, 16, 16, 3};
    const int COPs[8] = {64, 64, 64, 32, 32, 16, 16, 16};
    const int TGs[8]  = {16, 16, 16, 16, 16, 32, 32, 32};
    const int L = blockIdx.y;
    const int CI = CIs[L], CO = COs[L], COP = COPs[L], TG = TGs[L];
    const int K = 27 * CI, KP = (K + 31) & ~31;
    const int total = COP * KP;
    for (int i = blockIdx.x * 256 + threadIdx.x; i < total; i += gridDim.x * 256) {
        int jp = i / KP;          // out channel (padded)
        int kp = i - jp * KP;     // k (padded)
        float v = (jp < CO && kp < K) ? a.W[L][(size_t)kp * CO + jp] : 0.f;
        a.dst[L][((size_t)(kp / TG) * COP + jp) * TG + (kp % TG)] = (HALF)v;
    }
}

__global__ void convert_x_kernel(const float* __restrict__ x, HALF* __restrict__ xh, int total)
{
    int i = blockIdx.x * 256 + threadIdx.x;
    if (i < total) xh[i] = (HALF)x[i];
}

// ======================================================================
// 32x32x16 conv: 32-row m-tiles, NMT=2 -> 64 rows/wave (halved B traffic).
// Barrier-free, branch-free, depth-1 software prefetch.
// A frag: m=lane&31, k=(lane>>5)*8+j.  B frag: n=lane&31, k=(lane>>5)*8+j.
// C/D: col=lane&31, row=(reg&3)+8*(reg>>2)+4*(lane>>5)   [m74/m101 verified]
// ======================================================================
template<int CI, int CO_PAD, int NMT, bool FUSED>
__global__ __launch_bounds__(256, 2) void conv32_kernel(
    const HALF* __restrict__ h, const int* __restrict__ nbr,
    const HALF* __restrict__ Wt, HALF* __restrict__ yout,
    float* __restrict__ sums, int n,
    const float* __restrict__ psums, const float* __restrict__ pg,
    const float* __restrict__ pb, float pinvn)
{
    constexpr int K    = 27 * CI;
    constexpr int NCH  = K / 16;                 // 16-k chunks (K divisible by 16)
    constexpr int NJB  = CO_PAD / 32;
    constexpr int NW   = 4;
    constexpr int LOG2CI = (CI == 64) ? 6 : 5;
    constexpr int CPT  = CI / 16;                // chunks per tap (4 or 2)
    constexpr int NCB  = CPT;                    // distinct channel-base variants per lane

    __shared__ float red[2][NW][CO_PAD];

    const int wv   = threadIdx.x >> 6;
    const int lane = threadIdx.x & 63;
    const int l31  = lane & 31;
    const int lq2  = lane >> 5;                  // 0 or 1
    const int waveRow = blockIdx.x * (NW * 32 * NMT) + wv * (32 * NMT);

    f32x16 acc[NMT][NJB];
#pragma unroll
    for (int mt = 0; mt < NMT; ++mt)
#pragma unroll
        for (int jb = 0; jb < NJB; ++jb)
#pragma unroll
            for (int r = 0; r < 16; ++r) acc[mt][jb][r] = 0.f;

    // preload all 27 neighbor indices per m-tile (row = waveRow + mt*32 + l31)
    int idxr[NMT][27];
#pragma unroll
    for (int mt = 0; mt < NMT; ++mt) {
        const int row  = waveRow + mt * 32 + l31;
        const bool rok = row < n;
        const int* nb  = nbr + (size_t)min(row, n - 1) * 27;
#pragma unroll
        for (int t = 0; t < 27; ++t) {
            const int v = nb[t];
            idxr[mt][t] = rok ? v : -1;
        }
    }

    // per-lane BN constants: channel c = cb*16 + lq2*8 + j, cb = kc % CPT
    f16x8 sc8[NCB], bi8[NCB];
    if constexpr (FUSED) {
#pragma unroll
        for (int cb = 0; cb < NCB; ++cb) {
            const int c0 = cb * 16 + (lq2 << 3);
#pragma unroll
            for (int j = 0; j < 8; ++j) {
                const int c = c0 + j;
                const float mu  = psums[c] * pinvn;
                const float var = psums[CI + c] * pinvn - mu * mu;
                const float sc  = rsqrtf(var + 1e-3f) * pg[c];
                sc8[cb][j] = (HALF)sc;
                bi8[cb][j] = (HALF)(pb[c] - mu * sc);
            }
        }
    }

    // ---- depth-1 software-pipelined K loop
    f16x8 aC[NMT], bC[NJB];
    int   iC[NMT];
    // load chunk 0
#pragma unroll
    for (int mt = 0; mt < NMT; ++mt) {
        const int idx = idxr[mt][0];
        iC[mt] = idx;
        aC[mt] = *(const f16x8*)(h + (max(idx, 0) << LOG2CI) + (lq2 << 3));
    }
#pragma unroll
    for (int jb = 0; jb < NJB; ++jb)
        bC[jb] = *(const f16x8*)(Wt + (size_t)(jb * 32 + l31) * 16 + (lq2 << 3));

#pragma unroll
    for (int kc = 0; kc < NCH; ++kc) {
        // prefetch chunk kc+1
        f16x8 aN[NMT], bN[NJB];
        int   iN[NMT];
        if (kc + 1 < NCH) {
            const int slot = (kc + 1) / CPT;
            const int c    = ((kc + 1) % CPT) * 16 + (lq2 << 3);
#pragma unroll
            for (int mt = 0; mt < NMT; ++mt) {
                const int idx = idxr[mt][slot];
                iN[mt] = idx;
                aN[mt] = *(const f16x8*)(h + (max(idx, 0) << LOG2CI) + c);
            }
#pragma unroll
            for (int jb = 0; jb < NJB; ++jb)
                bN[jb] = *(const f16x8*)(Wt + ((size_t)(kc + 1) * CO_PAD + jb * 32 + l31) * 16 + (lq2 << 3));
        }

        // compute current chunk
        const int ccb = kc % CPT;
#pragma unroll
        for (int mt = 0; mt < NMT; ++mt) {
            f16x8 a = aC[mt];
            if constexpr (FUSED) {
                a = a * sc8[ccb] + bi8[ccb];
#pragma unroll
                for (int j = 0; j < 8; ++j)
                    a[j] = (a[j] < (HALF)0.f) ? (HALF)0.f : a[j];
            }
            const int m = ~(iC[mt] >> 31);
            i32x4 ai = __builtin_bit_cast(i32x4, a);
            ai.x &= m; ai.y &= m; ai.z &= m; ai.w &= m;
            a = __builtin_bit_cast(f16x8, ai);
#pragma unroll
            for (int jb = 0; jb < NJB; ++jb)
                acc[mt][jb] = __builtin_amdgcn_mfma_f32_32x32x16_f16(a, bC[jb], acc[mt][jb], 0, 0, 0);
        }
        if (kc + 1 < NCH) {
#pragma unroll
            for (int mt = 0; mt < NMT; ++mt) { aC[mt] = aN[mt]; iC[mt] = iN[mt]; }
#pragma unroll
            for (int jb = 0; jb < NJB; ++jb) bC[jb] = bN[jb];
        }
    }

    // ---- epilogue: store RAW pre-norm y + per-channel sum/sumsq
#pragma unroll
    for (int jb = 0; jb < NJB; ++jb) {
        const int col = jb * 32 + l31;
        float s = 0.f, sq = 0.f;
#pragma unroll
        for (int mt = 0; mt < NMT; ++mt) {
#pragma unroll
            for (int r = 0; r < 16; ++r) {
                const int row = waveRow + mt * 32 + (r & 3) + 8 * (r >> 2) + 4 * lq2;
                if (row < n) {
                    const float v = acc[mt][jb][r];
                    yout[(size_t)row * CO_PAD + col] = (HALF)v;
                    s += v;
                    sq += v * v;
                }
            }
        }
        s += __shfl_xor(s, 32); sq += __shfl_xor(sq, 32);
        if (lane < 32) { red[0][wv][col] = s; red[1][wv][col] = sq; }
    }
    __syncthreads();
    if (threadIdx.x < CO_PAD) {
        float s = 0.f, sq = 0.f;
#pragma unroll
        for (int w = 0; w < NW; ++w) { s += red[0][w][threadIdx.x]; sq += red[1][w][threadIdx.x]; }
        atomicAdd(&sums[threadIdx.x], s);
        atomicAdd(&sums[CO_PAD + threadIdx.x], sq);
    }
}

// ======================================================================
// 16x16x32 conv (round-4 proven config) for the CO_PAD=16 tail layers.
// ======================================================================
template<int CI, int CO_PAD, int NMT, bool FUSED>
__global__ __launch_bounds__(256, 2) void conv_kernel(
    const HALF* __restrict__ h, const int* __restrict__ nbr,
    const HALF* __restrict__ Wt, HALF* __restrict__ yout,
    float* __restrict__ sums, int n,
    const float* __restrict__ psums, const float* __restrict__ pg,
    const float* __restrict__ pb, float pinvn)
{
    constexpr int K    = 27 * CI;
    constexpr int KP   = (K + 31) & ~31;
    constexpr int NCH  = KP / 32;
    constexpr int NJB  = CO_PAD / 16;
    constexpr int NW   = 4;
    constexpr int NCB  = (CI >= 64) ? 2 : 1;
    constexpr int LOG2CI = (CI == 64) ? 6 : ((CI == 32) ? 5 : 4);
    constexpr int NIDX = (CI == 16) ? 14 : 27;

    __shared__ float red[2][NW][CO_PAD];

    const int wv   = threadIdx.x >> 6;
    const int lane = threadIdx.x & 63;
    const int l15  = lane & 15;
    const int lq   = lane >> 4;
    const int waveRow = blockIdx.x * (NW * 16 * NMT) + wv * (16 * NMT);

    f32x4 acc[NMT][NJB];
#pragma unroll
    for (int mt = 0; mt < NMT; ++mt)
#pragma unroll
        for (int jb = 0; jb < NJB; ++jb)
#pragma unroll
            for (int r = 0; r < 4; ++r) acc[mt][jb][r] = 0.f;

    int idxr[NMT][NIDX];
#pragma unroll
    for (int mt = 0; mt < NMT; ++mt) {
        const int row  = waveRow + mt * 16 + l15;
        const bool rok = row < n;
        const int* nb  = nbr + (size_t)min(row, n - 1) * 27;
#pragma unroll
        for (int s = 0; s < NIDX; ++s) {
            const int t = (CI == 16) ? (2 * s + (lq >> 1)) : s;
            const int v = nb[t < 27 ? t : 26];
            idxr[mt][s] = (rok && t < 27) ? v : -1;
        }
    }

    f16x8 sc8[NCB], bi8[NCB];
    if constexpr (FUSED) {
#pragma unroll
        for (int cb = 0; cb < NCB; ++cb) {
            const int c0 = cb * 32 + ((lq * 8) & (CI - 1));
#pragma unroll
            for (int j = 0; j < 8; ++j) {
                const int c = c0 + j;
                const float mu  = psums[c] * pinvn;
                const float var = psums[CI + c] * pinvn - mu * mu;
                const float sc  = rsqrtf(var + 1e-3f) * pg[c];
                sc8[cb][j] = (HALF)sc;
                bi8[cb][j] = (HALF)(pb[c] - mu * sc);
            }
        }
    }

#pragma unroll
    for (int kc = 0; kc < NCH; ++kc) {
        const int c    = (kc * 32 + lq * 8) & (CI - 1);
        const int slot = (CI == 64) ? (kc >> 1) : kc;
        const int ccb  = (NCB == 2) ? (kc & 1) : 0;

        const HALF* wb = Wt + (size_t)kc * (CO_PAD * 32) + lq * 8;
        f16x8 b[NJB];
#pragma unroll
        for (int jb = 0; jb < NJB; ++jb)
            b[jb] = *(const f16x8*)(wb + (size_t)(jb * 16 + l15) * 32);

#pragma unroll
        for (int mt = 0; mt < NMT; ++mt) {
            const int idx = idxr[mt][slot];
            const int off = (max(idx, 0) << LOG2CI) + c;
            f16x8 a = *(const f16x8*)(h + off);
            if constexpr (FUSED) {
                a = a * sc8[ccb] + bi8[ccb];
#pragma unroll
                for (int j = 0; j < 8; ++j)
                    a[j] = (a[j] < (HALF)0.f) ? (HALF)0.f : a[j];
            }
            const int m = ~(idx >> 31);
            i32x4 ai = __builtin_bit_cast(i32x4, a);
            ai.x &= m; ai.y &= m; ai.z &= m; ai.w &= m;
            a = __builtin_bit_cast(f16x8, ai);
#pragma unroll
            for (int jb = 0; jb < NJB; ++jb)
                acc[mt][jb] = __builtin_amdgcn_mfma_f32_16x16x32_f16(a, b[jb], acc[mt][jb], 0, 0, 0);
        }
    }

#pragma unroll
    for (int jb = 0; jb < NJB; ++jb) {
        const int col = jb * 16 + l15;
        float s = 0.f, sq = 0.f;
#pragma unroll
        for (int mt = 0; mt < NMT; ++mt) {
            const int rb = waveRow + mt * 16 + lq * 4;
#pragma unroll
            for (int r = 0; r < 4; ++r) {
                if (rb + r < n) {
                    const float v = acc[mt][jb][r];
                    yout[(size_t)(rb + r) * CO_PAD + col] = (HALF)v;
                    s += v;
                    sq += v * v;
                }
            }
        }
        s  += __shfl_xor(s, 16);  s  += __shfl_xor(s, 32);
        sq += __shfl_xor(sq, 16); sq += __shfl_xor(sq, 32);
        if (lane < 16) { red[0][wv][col] = s; red[1][wv][col] = sq; }
    }
    __syncthreads();
    if (threadIdx.x < CO_PAD) {
        float s = 0.f, sq = 0.f;
#pragma unroll
        for (int w = 0; w < NW; ++w) { s += red[0][w][threadIdx.x]; sq += red[1][w][threadIdx.x]; }
        atomicAdd(&sums[threadIdx.x], s);
        atomicAdd(&sums[CO_PAD + threadIdx.x], sq);
    }
}

// ---- final: normalize (no relu), co=3 out of CO_PAD=16, fp32 output
__global__ void bn_out_kernel(const HALF* __restrict__ y, const float* __restrict__ sums,
                              const float* __restrict__ g, const float* __restrict__ b,
                              int n, float invn, float* __restrict__ out)
{
    int i = blockIdx.x * 256 + threadIdx.x;
    if (i >= n * 3) return;
    int row = i / 3;
    int c = i - row * 3;
    float mu  = sums[c] * invn;
    float var = sums[16 + c] * invn - mu * mu;
    float sc  = rsqrtf(var + 1e-3f) * g[c];
    out[i] = ((float)y[(size_t)row * 16 + c] - mu) * sc + b[c];
}

extern "C" void kernel_launch(void* const* d_in, const int* in_sizes, int n_in,
                              void* d_out, int out_size, void* d_ws, size_t ws_size,
                              hipStream_t stream)
{
    const int* nbr4  = (const int*)d_in[0];
    const int* inv43 = (const int*)d_in[1];
    const int* nbr3  = (const int*)d_in[2];
    const int* inv32 = (const int*)d_in[3];
    const int* nbr2  = (const int*)d_in[4];
    const int* inv21 = (const int*)d_in[5];
    const int* nbr1  = (const int*)d_in[6];
    const float* x   = (const float*)d_in[7];

    const int n4 = in_sizes[0] / 27;
    const int n3 = in_sizes[1] / 27;
    const int n2 = in_sizes[3] / 27;
    const int n1 = in_sizes[5] / 27;

    // specs: m4,i4,m3,i3,m2,i2,m1,c5
    const int CIs[8]  = {64, 64, 64, 64, 32, 32, 16, 16};
    const int COPs[8] = {64, 64, 64, 32, 32, 16, 16, 16};
    int KPs[8], wtoff[8];
    int wtot = 0;
    for (int s = 0; s < 8; ++s) {
        KPs[s] = ((27 * CIs[s] + 31) / 32) * 32;
        wtoff[s] = wtot;
        wtot += COPs[s] * KPs[s];
    }

    char* ws = (char*)d_ws;
    HALF* wt = (HALF*)ws;
    size_t off = ((size_t)wtot * sizeof(HALF) + 255) & ~(size_t)255;
    float* sums = (float*)(ws + off);
    off += 8 * 128 * sizeof(float);
    off = (off + 255) & ~(size_t)255;
    HALF* xh = (HALF*)(ws + off);
    off += ((size_t)n4 * 64 * sizeof(HALF) + 255) & ~(size_t)255;
    size_t bufElems = 0;
    {
        size_t cand[4] = {(size_t)n4 * 64, (size_t)n3 * 64, (size_t)n2 * 32, (size_t)n1 * 16};
        for (int i = 0; i < 4; ++i) if (cand[i] > bufElems) bufElems = cand[i];
    }
    HALF* Y0 = (HALF*)(ws + off);
    off += (bufElems * sizeof(HALF) + 255) & ~(size_t)255;
    HALF* Y1 = (HALF*)(ws + off);

    hipMemsetAsync(sums, 0, 8 * 128 * sizeof(float), stream);

    WArgs wa;
    for (int s = 0; s < 8; ++s) { wa.W[s] = (const float*)d_in[8 + 3 * s]; wa.dst[s] = wt + wtoff[s]; }
    {
        int maxTotal = 64 * KPs[0];
        dim3 grid((maxTotal + 255) / 256, 8);
        convert_all_w_kernel<<<grid, 256, 0, stream>>>(wa);
    }
    convert_x_kernel<<<(n4 * 64 + 255) / 256, 256, 0, stream>>>(x, xh, n4 * 64);

#define G(s) ((const float*)d_in[9 + 3 * (s)])
#define B(s) ((const float*)d_in[10 + 3 * (s)])
#define SUMS(s) (sums + (s) * 128)
#define GRID32(nn) (((nn) + 255) / 256)
#define GRID16(nn) (((nn) + 127) / 128)

    // m4: xh(n4,64) -> Y0 (raw)
    conv32_kernel<64, 64, 2, false><<<GRID32(n4), 256, 0, stream>>>(
        xh, nbr4, wt + wtoff[0], Y0, SUMS(0), n4, nullptr, nullptr, nullptr, 0.f);
    // i4: norm(m4) fused; Y0(n4) -> Y1(n3)
    conv32_kernel<64, 64, 2, true><<<GRID32(n3), 256, 0, stream>>>(
        Y0, inv43, wt + wtoff[1], Y1, SUMS(1), n3, SUMS(0), G(0), B(0), 1.f / n4);
    // m3: norm(i4) fused; Y1 -> Y0
    conv32_kernel<64, 64, 2, true><<<GRID32(n3), 256, 0, stream>>>(
        Y1, nbr3, wt + wtoff[2], Y0, SUMS(2), n3, SUMS(1), G(1), B(1), 1.f / n3);
    // i3: norm(m3) fused; Y0(n3) -> Y1(n2), co 32
    conv32_kernel<64, 32, 2, true><<<GRID32(n2), 256, 0, stream>>>(
        Y0, inv32, wt + wtoff[3], Y1, SUMS(3), n2, SUMS(2), G(2), B(2), 1.f / n3);
    // m2: norm(i3) fused; Y1 -> Y0
    conv32_kernel<32, 32, 2, true><<<GRID32(n2), 256, 0, stream>>>(
        Y1, nbr2, wt + wtoff[4], Y0, SUMS(4), n2, SUMS(3), G(3), B(3), 1.f / n2);
    // i2: norm(m2) fused; Y0(n2) -> Y1(n1), co 16
    conv_kernel<32, 16, 2, true><<<GRID16(n1), 256, 0, stream>>>(
        Y0, inv21, wt + wtoff[5], Y1, SUMS(5), n1, SUMS(4), G(4), B(4), 1.f / n2);
    // m1: norm(i2) fused; Y1 -> Y0
    conv_kernel<16, 16, 2, true><<<GRID16(n1), 256, 0, stream>>>(
        Y1, nbr1, wt + wtoff[6], Y0, SUMS(6), n1, SUMS(5), G(5), B(5), 1.f / n1);
    // c5: norm(m1) fused; Y0 -> Y1 (raw), then fp32 out
    conv_kernel<16, 16, 2, true><<<GRID16(n1), 256, 0, stream>>>(
        Y0, nbr1, wt + wtoff[7], Y1, SUMS(7), n1, SUMS(6), G(6), B(6), 1.f / n1);
    bn_out_kernel<<<(n1 * 3 + 255) / 256, 256, 0, stream>>>(
        Y1, SUMS(7), G(7), B(7), n1, 1.f / n1, (float*)d_out);

#undef G
#undef B
#undef SUMS
#undef GRID32
#undef GRID16
}

// Round 9
// 1057.516 us; speedup vs baseline: 1.4744x; 1.4744x over previous
//
#include <hip/hip_runtime.h>

typedef _Float16 HALF;
typedef _Float16 f16x8 __attribute__((ext_vector_type(8)));
typedef float f32x4 __attribute__((ext_vector_type(4)));

// ---- weight conversion: fp32 (27*CI, CO) -> fp16 in MFMA-fragment-permuted order:
// dst[ ((kc*NJB + jb)*64 + lane)*8 + j ] = W[k = kc*32 + (lane>>4)*8 + j][co = jb*16 + (lane&15)]
// so a linear 256-thread copy into LDS gives conflict-free ds_read_b128 fragments.
struct WArgs { const float* W[8]; HALF* dst[8]; };

__global__ void convert_all_w_kernel(WArgs a)
{
    const int CIs[8]  = {64, 64, 64, 64, 32, 32, 16, 16};
    const int COs[8]  = {64, 64, 64, 32, 32, 16, 16, 3};
    const int COPs[8] = {64, 64, 64, 32, 32, 16, 16, 16};
    const int L = blockIdx.y;
    const int CI = CIs[L], CO = COs[L], COP = COPs[L];
    const int K = 27 * CI, KP = (K + 31) & ~31, NCH = KP / 32, NJB = COP / 16;
    const int total = NCH * NJB * 512;
    for (int e = blockIdx.x * 256 + threadIdx.x; e < total; e += gridDim.x * 256) {
        const int j    = e & 7;
        const int u    = e >> 3;
        const int lane = u & 63;
        const int q    = u >> 6;          // kc*NJB + jb
        const int jb   = q % NJB;
        const int kc   = q / NJB;
        const int k    = kc * 32 + (lane >> 4) * 8 + j;
        const int co   = jb * 16 + (lane & 15);
        const float v  = (k < K && co < CO) ? a.W[L][(size_t)k * CO + co] : 0.f;
        a.dst[L][e] = (HALF)v;
    }
}

__global__ void convert_x_kernel(const float* __restrict__ x, HALF* __restrict__ xh,
                                 int total, int pad)
{
    int i = blockIdx.x * 256 + threadIdx.x;
    if (i < total) xh[i] = (HALF)x[i];
    else if (i < total + pad) xh[i] = (HALF)0.f;   // zero sentinel row
}

// ---- conv: 16x16x32 MFMA, 32 rows/wave (NMT=2), 128 rows/block.
// A: direct global->register gathers; invalid taps -> PRODUCER's sentinel row hn
//    (hn = producer row count; BN(sentinel) == 0).
// B: block-shared, double-buffered LDS staging via explicit vector loads + ds_write
//    (1 barrier per GRP chunks). FUSED: producer BN+ReLU applied during gather.
// Epilogue: raw y + sum/sumsq atomics + last-block sentinel-row write at row n.
template<int CI, int CO_PAD, int GRP, bool FUSED>
__global__ __launch_bounds__(256, 2) void conv_kernel(
    const HALF* __restrict__ h, const int* __restrict__ nbr,
    const HALF* __restrict__ Wt, HALF* __restrict__ yout,
    float* __restrict__ sums, int* __restrict__ counter, int n, int hn,
    const float* __restrict__ psums, const float* __restrict__ pg,
    const float* __restrict__ pb, float pinvn,
    const float* __restrict__ og, const float* __restrict__ ob, float oinvn)
{
    constexpr int K    = 27 * CI;
    constexpr int KP   = (K + 31) & ~31;
    constexpr int NCH  = KP / 32;
    constexpr int NJB  = CO_PAD / 16;
    constexpr int NMT  = 2;
    constexpr int NG   = (NCH + GRP - 1) / GRP;
    constexpr int LOG2CI = (CI == 64) ? 6 : ((CI == 32) ? 5 : 4);
    constexpr int NIDX = (CI == 16) ? 14 : 27;
    constexpr int NCB  = (CI == 64) ? 2 : 1;
    constexpr int SITER = GRP * NJB * 64 / 256;   // f16x8 units per thread per group

    __shared__ __align__(16) HALF bst[2][GRP * NJB * 512];
    __shared__ float red[2][4][CO_PAD];
    __shared__ int isLast;

    const int tid  = threadIdx.x;
    const int wv   = tid >> 6;
    const int lane = tid & 63;
    const int l15  = lane & 15;
    const int lq   = lane >> 4;
    const int waveRow = blockIdx.x * 128 + wv * 32;

    f32x4 acc[NMT][NJB];
#pragma unroll
    for (int mt = 0; mt < NMT; ++mt)
#pragma unroll
        for (int jb = 0; jb < NJB; ++jb)
#pragma unroll
            for (int r = 0; r < 4; ++r) acc[mt][jb][r] = 0.f;

    // preload neighbor indices as half-offsets; invalid -> PRODUCER sentinel row hn
    int idxr[NMT][NIDX];
#pragma unroll
    for (int mt = 0; mt < NMT; ++mt) {
        const int row  = waveRow + mt * 16 + l15;
        const bool rok = row < n;
        const int* nb  = nbr + (size_t)(rok ? row : (n - 1)) * 27;
#pragma unroll
        for (int s = 0; s < NIDX; ++s) {
            const int t = (CI == 16) ? (2 * s + (lq >> 1)) : s;
            const int v = nb[t < 27 ? t : 26];
            const int id = (rok && t < 27 && v >= 0) ? v : hn;
            idxr[mt][s] = id << LOG2CI;
        }
    }

    // per-lane BN constants for this lane's gathered channel slots
    f16x8 sc8[NCB], bi8[NCB];
    if constexpr (FUSED) {
#pragma unroll
        for (int cb = 0; cb < NCB; ++cb) {
            const int c0 = cb * 32 + ((lq * 8) & (CI - 1));
#pragma unroll
            for (int j = 0; j < 8; ++j) {
                const int c = c0 + j;
                const float mu  = psums[c] * pinvn;
                const float var = psums[CI + c] * pinvn - mu * mu;
                const float sc  = rsqrtf(var + 1e-3f) * pg[c];
                sc8[cb][j] = (HALF)sc;
                bi8[cb][j] = (HALF)(pb[c] - mu * sc);
            }
        }
    }

    // stage group 0: global -> regs -> LDS
    {
        f16x8 stg[SITER];
#pragma unroll
        for (int i = 0; i < SITER; ++i)
            stg[i] = *(const f16x8*)(Wt + ((size_t)i * 256 + tid) * 8);
#pragma unroll
        for (int i = 0; i < SITER; ++i)
            *(f16x8*)&bst[0][((size_t)i * 256 + tid) * 8] = stg[i];
    }
    __syncthreads();

#pragma unroll
    for (int g = 0; g < NG; ++g) {
        f16x8 stg[SITER];
        if (g + 1 < NG) {   // issue next group's global loads early (overlap with compute)
            const HALF* gs = Wt + (size_t)(g + 1) * GRP * NJB * 512 + (size_t)tid * 8;
#pragma unroll
            for (int i = 0; i < SITER; ++i)
                stg[i] = *(const f16x8*)(gs + (size_t)i * 2048);
        }
#pragma unroll
        for (int ki = 0; ki < GRP; ++ki) {
            if (g * GRP + ki < NCH) {
                const int kc = g * GRP + ki;
                f16x8 b[NJB];
#pragma unroll
                for (int jb = 0; jb < NJB; ++jb)
                    b[jb] = *(const f16x8*)&bst[g & 1][((ki * NJB + jb) * 64 + lane) * 8];
                const int c    = (kc * 32 + lq * 8) & (CI - 1);
                const int slot = (CI == 64) ? (kc >> 1) : kc;
                const int ccb  = (NCB == 2) ? (kc & 1) : 0;
#pragma unroll
                for (int mt = 0; mt < NMT; ++mt) {
                    f16x8 a = *(const f16x8*)(h + idxr[mt][slot] + c);
                    if constexpr (FUSED) {
                        a = a * sc8[ccb] + bi8[ccb];
#pragma unroll
                        for (int j = 0; j < 8; ++j)
                            a[j] = (a[j] < (HALF)0.f) ? (HALF)0.f : a[j];
                    }
#pragma unroll
                    for (int jb = 0; jb < NJB; ++jb)
                        acc[mt][jb] = __builtin_amdgcn_mfma_f32_16x16x32_f16(a, b[jb], acc[mt][jb], 0, 0, 0);
                }
            }
        }
        if (g + 1 < NG) {   // write staged regs to the other buffer (its readers finished last barrier)
#pragma unroll
            for (int i = 0; i < SITER; ++i)
                *(f16x8*)&bst[(g + 1) & 1][((size_t)i * 256 + tid) * 8] = stg[i];
        }
        __syncthreads();
    }

    // ---- epilogue: raw y store + per-channel sum/sumsq
#pragma unroll
    for (int jb = 0; jb < NJB; ++jb) {
        const int col = jb * 16 + l15;
        float s = 0.f, sq = 0.f;
#pragma unroll
        for (int mt = 0; mt < NMT; ++mt) {
            const int rb = waveRow + mt * 16 + lq * 4;
#pragma unroll
            for (int r = 0; r < 4; ++r) {
                if (rb + r < n) {
                    const float v = acc[mt][jb][r];
                    yout[(size_t)(rb + r) * CO_PAD + col] = (HALF)v;
                    s += v;
                    sq += v * v;
                }
            }
        }
        s  += __shfl_xor(s, 16);  s  += __shfl_xor(s, 32);
        sq += __shfl_xor(sq, 16); sq += __shfl_xor(sq, 32);
        if (lane < 16) { red[0][wv][col] = s; red[1][wv][col] = sq; }
    }
    __syncthreads();
    if (tid < CO_PAD) {
        float s = 0.f, sq = 0.f;
#pragma unroll
        for (int w = 0; w < 4; ++w) { s += red[0][w][tid]; sq += red[1][w][tid]; }
        atomicAdd(&sums[tid], s);
        atomicAdd(&sums[CO_PAD + tid], sq);
    }
    // ---- last block writes the sentinel row at row n: BN(sent) == 0 for consumers
    __threadfence();
    __syncthreads();
    if (tid == 0) isLast = (atomicAdd(counter, 1) == (int)gridDim.x - 1) ? 1 : 0;
    __syncthreads();
    if (isLast && tid < CO_PAD) {
        const float s  = atomicAdd(&sums[tid], 0.f);
        const float sq = atomicAdd(&sums[CO_PAD + tid], 0.f);
        const float mu  = s * oinvn;
        const float var = sq * oinvn - mu * mu;
        const float sc  = rsqrtf(var + 1e-3f) * og[tid];
        const float bi  = ob[tid] - mu * sc;
        const float sent = (fabsf(sc) > 1e-20f) ? (-bi / sc) : 0.f;
        yout[(size_t)n * CO_PAD + tid] = (HALF)sent;
    }
}

// ---- final: normalize (no relu), co=3 out of CO_PAD=16, fp32 output
__global__ void bn_out_kernel(const HALF* __restrict__ y, const float* __restrict__ sums,
                              const float* __restrict__ g, const float* __restrict__ b,
                              int n, float invn, float* __restrict__ out)
{
    int i = blockIdx.x * 256 + threadIdx.x;
    if (i >= n * 3) return;
    int row = i / 3;
    int c = i - row * 3;
    float mu  = sums[c] * invn;
    float var = sums[16 + c] * invn - mu * mu;
    float sc  = rsqrtf(var + 1e-3f) * g[c];
    out[i] = ((float)y[(size_t)row * 16 + c] - mu) * sc + b[c];
}

extern "C" void kernel_launch(void* const* d_in, const int* in_sizes, int n_in,
                              void* d_out, int out_size, void* d_ws, size_t ws_size,
                              hipStream_t stream)
{
    const int* nbr4  = (const int*)d_in[0];
    const int* inv43 = (const int*)d_in[1];
    const int* nbr3  = (const int*)d_in[2];
    const int* inv32 = (const int*)d_in[3];
    const int* nbr2  = (const int*)d_in[4];
    const int* inv21 = (const int*)d_in[5];
    const int* nbr1  = (const int*)d_in[6];
    const float* x   = (const float*)d_in[7];

    const int n4 = in_sizes[0] / 27;
    const int n3 = in_sizes[1] / 27;
    const int n2 = in_sizes[3] / 27;
    const int n1 = in_sizes[5] / 27;

    // specs: m4,i4,m3,i3,m2,i2,m1,c5
    const int CIs[8]  = {64, 64, 64, 64, 32, 32, 16, 16};
    const int COPs[8] = {64, 64, 64, 32, 32, 16, 16, 16};
    const int GRPs[8] = {6, 6, 6, 8, 8, 8, 8, 8};
    int wtoff[8];
    int wtot = 0;
    for (int s = 0; s < 8; ++s) {
        int KP  = ((27 * CIs[s] + 31) / 32) * 32;
        int NCH = KP / 32;
        int NG  = (NCH + GRPs[s] - 1) / GRPs[s];
        wtoff[s] = wtot;
        wtot += NG * GRPs[s] * COPs[s] * 32;   // padded to group boundary
    }

    char* ws = (char*)d_ws;
    HALF* wt = (HALF*)ws;
    size_t off = ((size_t)wtot * sizeof(HALF) + 255) & ~(size_t)255;
    float* sums = (float*)(ws + off);
    int* counters = (int*)(ws + off + 8 * 128 * sizeof(float));
    off += 8 * 128 * sizeof(float) + 8 * sizeof(int);
    off = (off + 255) & ~(size_t)255;
    HALF* xh = (HALF*)(ws + off);
    off += (((size_t)n4 * 64 + 64) * sizeof(HALF) + 255) & ~(size_t)255;
    size_t bufElems = 64;
    {
        size_t cand[4] = {(size_t)n4 * 64, (size_t)n3 * 64, (size_t)n2 * 32, (size_t)n1 * 16};
        for (int i = 0; i < 4; ++i) if (cand[i] + 64 > bufElems) bufElems = cand[i] + 64;
    }
    HALF* Y0 = (HALF*)(ws + off);
    off += (bufElems * sizeof(HALF) + 255) & ~(size_t)255;
    HALF* Y1 = (HALF*)(ws + off);

    hipMemsetAsync(sums, 0, 8 * 128 * sizeof(float) + 8 * sizeof(int), stream);

    WArgs wa;
    for (int s = 0; s < 8; ++s) { wa.W[s] = (const float*)d_in[8 + 3 * s]; wa.dst[s] = wt + wtoff[s]; }
    {
        dim3 grid(432, 8);
        convert_all_w_kernel<<<grid, 256, 0, stream>>>(wa);
    }
    convert_x_kernel<<<(n4 * 64 + 64 + 255) / 256, 256, 0, stream>>>(x, xh, n4 * 64, 64);

#define G(s) ((const float*)d_in[9 + 3 * (s)])
#define B(s) ((const float*)d_in[10 + 3 * (s)])
#define SUMS(s) (sums + (s) * 128)
#define GRID(nn) (((nn) + 127) / 128)

    // m4: xh(n4,64) -> Y0 (raw). producer sentinel row = n4 (xh zero pad)
    conv_kernel<64, 64, 6, false><<<GRID(n4), 256, 0, stream>>>(
        xh, nbr4, wt + wtoff[0], Y0, SUMS(0), counters + 0, n4, n4,
        nullptr, nullptr, nullptr, 0.f, G(0), B(0), 1.f / n4);
    // i4: norm(m4) fused; Y0(n4 rows, sentinel@n4) -> Y1(n3)
    conv_kernel<64, 64, 6, true><<<GRID(n3), 256, 0, stream>>>(
        Y0, inv43, wt + wtoff[1], Y1, SUMS(1), counters + 1, n3, n4,
        SUMS(0), G(0), B(0), 1.f / n4, G(1), B(1), 1.f / n3);
    // m3: norm(i4) fused; Y1(sentinel@n3) -> Y0
    conv_kernel<64, 64, 6, true><<<GRID(n3), 256, 0, stream>>>(
        Y1, nbr3, wt + wtoff[2], Y0, SUMS(2), counters + 2, n3, n3,
        SUMS(1), G(1), B(1), 1.f / n3, G(2), B(2), 1.f / n3);
    // i3: norm(m3) fused; Y0(n3 rows, sentinel@n3) -> Y1(n2), co 32
    conv_kernel<64, 32, 8, true><<<GRID(n2), 256, 0, stream>>>(
        Y0, inv32, wt + wtoff[3], Y1, SUMS(3), counters + 3, n2, n3,
        SUMS(2), G(2), B(2), 1.f / n3, G(3), B(3), 1.f / n2);
    // m2: norm(i3) fused; Y1(sentinel@n2) -> Y0
    conv_kernel<32, 32, 8, true><<<GRID(n2), 256, 0, stream>>>(
        Y1, nbr2, wt + wtoff[4], Y0, SUMS(4), counters + 4, n2, n2,
        SUMS(3), G(3), B(3), 1.f / n2, G(4), B(4), 1.f / n2);
    // i2: norm(m2) fused; Y0(n2 rows, sentinel@n2) -> Y1(n1), co 16
    conv_kernel<32, 16, 8, true><<<GRID(n1), 256, 0, stream>>>(
        Y0, inv21, wt + wtoff[5], Y1, SUMS(5), counters + 5, n1, n2,
        SUMS(4), G(4), B(4), 1.f / n2, G(5), B(5), 1.f / n1);
    // m1: norm(i2) fused; Y1(sentinel@n1) -> Y0
    conv_kernel<16, 16, 8, true><<<GRID(n1), 256, 0, stream>>>(
        Y1, nbr1, wt + wtoff[6], Y0, SUMS(6), counters + 6, n1, n1,
        SUMS(5), G(5), B(5), 1.f / n1, G(6), B(6), 1.f / n1);
    // c5: norm(m1) fused; Y0(sentinel@n1) -> Y1 (raw), then fp32 out
    conv_kernel<16, 16, 8, true><<<GRID(n1), 256, 0, stream>>>(
        Y0, nbr1, wt + wtoff[7], Y1, SUMS(7), counters + 7, n1, n1,
        SUMS(6), G(6), B(6), 1.f / n1, G(7), B(7), 1.f / n1);
    bn_out_kernel<<<(n1 * 3 + 255) / 256, 256, 0, stream>>>(
        Y1, SUMS(7), G(7), B(7), n1, 1.f / n1, (float*)d_out);

#undef G
#undef B
#undef SUMS
#undef GRID
}